// Round 10
// baseline (32.809 us; speedup 1.0000x reference)
//
#include <hip/hip_runtime.h>
#include <cfloat>

#define NS 7
#define NC 256
#define NH 64
#define NW 64
#define NR 128

#define RFL(x) __builtin_amdgcn_readfirstlane(x)

// Kernel 1: transpose (C,H,W) -> (H,W,C) into d_ws.
// Grid 1024 = 64 h * 4 c-quarters * 4 w-quarters. 1 f4 load + 1 f4 store/thread.
__global__ __launch_bounds__(256) void transpose_chw_hwc(
    const float* __restrict__ f, float* __restrict__ ft)
{
    __shared__ float tile[16][65];   // [w][c]
    const int tid = threadIdx.x;
    const int h   = blockIdx.x >> 4;
    const int c0  = ((blockIdx.x >> 2) & 3) * 64;
    const int w0  = (blockIdx.x & 3) * 16;

    {
        int c  = tid >> 2;            // 0..63
        int w4 = (tid & 3) * 4;       // 0,4,8,12
        float4 v = *(const float4*)(f + (size_t)(c0 + c) * (NH * NW) + h * NW + w0 + w4);
        tile[w4 + 0][c] = v.x;
        tile[w4 + 1][c] = v.y;
        tile[w4 + 2][c] = v.z;
        tile[w4 + 3][c] = v.w;
    }
    __syncthreads();
    {
        int w  = tid >> 4;            // 0..15
        int c4 = (tid & 15) * 4;      // 0..60
        float4 v = make_float4(tile[w][c4 + 0], tile[w][c4 + 1],
                               tile[w][c4 + 2], tile[w][c4 + 3]);
        *(float4*)(ft + (size_t)h * (NW * NC) + (w0 + w) * NC + c0 + c4) = v;
    }
}

// Kernel 2: wave = (r, bin, c-group of 64), lane = channel.
// All bounds wave-uniform scalars; loads saddr+voffset (0 VALU/load),
// coalesced 256B; w-window unrolled x4 with scalar clamped dup reads.
__global__ __launch_bounds__(256) void roi_pool_hwc(
    const float* __restrict__ ft, const int* __restrict__ rois,
    float* __restrict__ out)
{
    const int lane = threadIdx.x & 63;
    const int wv   = threadIdx.x >> 6;
    const int W    = blockIdx.x * 4 + wv;          // 0..25087

    const int cg  = RFL(W & 3);
    const int rb_ = W >> 2;                        // r*49 + bin
    const int bin = RFL(rb_ % (NS * NS));
    const int r   = RFL(rb_ / (NS * NS));
    const int i   = bin / NS;
    const int j   = bin - i * NS;

    const int4 rq = ((const int4*)rois)[r];
    const int x1 = RFL(rq.x), y1 = RFL(rq.y), x2 = RFL(rq.z), y2 = RFL(rq.w);
    const int Lh = x2 - x1 + 1;
    const int Lw = y2 - y1 + 1;

    const int h0 = x1 + (i * Lh) / NS;
    const int h1 = x1 + ((i + 1) * Lh + NS - 1) / NS;
    const int w0 = y1 + (j * Lw) / NS;
    const int w1 = y1 + ((j + 1) * Lw + NS - 1) / NS;

    // per-lane base: channel offset; scalar part added per (h,w)
    const float* fcl = ft + cg * 64 + lane;

    float m = -FLT_MAX;
    for (int h = h0; h < h1; ++h) {                 // scalar loop, <= 11
        const size_t rowo = (size_t)(h * NW) * NC;
        for (int wg = w0; wg < w1; wg += 4) {       // scalar loop, 1..3 trips
            int wB = min(wg + 1, w1 - 1);           // clamped dup reads:
            int wC = min(wg + 2, w1 - 1);           // always in-window
            int wD = min(wg + 3, w1 - 1);
            float a = fcl[rowo + (size_t)wg * NC];  // 4 independent coalesced
            float b = fcl[rowo + (size_t)wB * NC];  // 256B loads, one waitcnt
            float c = fcl[rowo + (size_t)wC * NC];
            float d = fcl[rowo + (size_t)wD * NC];
            m = fmaxf(m, fmaxf(fmaxf(a, b), fmaxf(c, d)));
        }
    }

    out[((size_t)(r * NC + cg * 64 + lane)) * (NS * NS) + bin] = m;
}

extern "C" void kernel_launch(void* const* d_in, const int* in_sizes, int n_in,
                              void* d_out, int out_size, void* d_ws, size_t ws_size,
                              hipStream_t stream)
{
    const float* feature_map = (const float*)d_in[0];
    const int*   rois        = (const int*)d_in[1];
    float*       out         = (float*)d_out;
    float*       ft          = (float*)d_ws;   // 4 MB HWC scratch

    transpose_chw_hwc<<<1024, 256, 0, stream>>>(feature_map, ft);

    const int nwaves = NR * NS * NS * 4;       // 25088
    roi_pool_hwc<<<nwaves / 4, 256, 0, stream>>>(ft, rois, out);
}